// Round 5
// baseline (479.999 us; speedup 1.0000x reference)
//
#include <hip/hip_runtime.h>
#include <hip/hip_bf16.h>

// Symmetric contraction (MACE-style), B=2048, C=256, I=9, E=10. fp32 only
// (fp32 absmax 0.5 vs threshold 7.24; bf16/MFMA numerically dead).
//
// Round-5:
//  * T decomposition (validated r3/r4): out[b,c,ch] = sum_m sum_e y[b,e] *
//    phi_m(x[b,c,:]) * T[m,e,c,ch],  T = Sym x W built by parallel prep.
//  * ch-split: partition 0 -> (s,v0), partition 1 -> (v1,v2), blockIdx.y.
//    Doubles waves/SIMD to 2 (r4 was issue-stalled 33% at 1 wave/SIMD).
//    Disjoint out writes -> no combine pass. T stored as float2 per part.
//  * tsum restructure + v2f packed fp32 (__builtin_elementwise_fma ->
//    v_pk_fma_f32): fewer issue slots per FLOP.
//  * manual 2x m-unroll, A/B register buffers (no mov-copies), prefetch m+1.
//  * XCD swizzle keeps each XCD-pair's T c-slice L2-resident.
// r2 lesson: no waves/EU launch-bounds cap (spill disaster).

#define NB 2048
#define NC 256
#define NI 9
#define NE 10

#define N_TRI 165
#define N_PAIR 45
#define BT 8

typedef float v2f __attribute__((ext_vector_type(2)));

// float2 counts per partition region
#define A3N (N_TRI * NE * NC)    // 422400
#define A2N (N_PAIR * NE * NC)   // 115200
#define A1N (NI * NE * NC)       // 23040
#define PARTN (A3N + A2N + A1N)  // 560640 float2 = 4.485 MB; x2 parts = 8.97 MB

__device__ __forceinline__ v2f splat2(float s) { v2f r; r.x = s; r.y = s; return r; }

// ---------------- prep: Sym (LDS) x W -> T float2 pair tables ----------------
// grid (219, 10) x 256 threads.
__global__ __launch_bounds__(256) void sc_prep(
    const float* __restrict__ U1_s, const float* __restrict__ U2_s,
    const float* __restrict__ U3_s, const float* __restrict__ U1_v,
    const float* __restrict__ U2_v, const float* __restrict__ U3_v,
    const float* __restrict__ W1_s, const float* __restrict__ W2_s,
    const float* __restrict__ W3_s, const float* __restrict__ W1_v,
    const float* __restrict__ W2_v, const float* __restrict__ W3_v,
    float* __restrict__ ws)
{
    const int m = blockIdx.x;    // 0..218
    const int e = blockIdx.y;    // 0..9
    const int tid = threadIdx.x; // 0..255
    float2* __restrict__ TA3 = (float2*)ws;
    float2* __restrict__ TA2 = TA3 + A3N;
    float2* __restrict__ TA1 = TA2 + A2N;

    __shared__ float sym[128];

    if (m < N_TRI) {
        if (tid < 113) {
            int ii = 0, jj = 0, kk = 0, cnt = 0;
            for (int i = 0; i < NI; i++)
                for (int j = i; j < NI; j++)
                    for (int k = j; k < NI; k++) {
                        if (cnt == m) { ii = i; jj = j; kk = k; }
                        cnt++;
                    }
            int P[6][3]; int np;
            if (ii == jj && jj == kk) {
                np = 1;
                P[0][0] = ii; P[0][1] = ii; P[0][2] = ii;
            } else if (ii == jj) {
                np = 3;
                P[0][0] = ii; P[0][1] = ii; P[0][2] = kk;
                P[1][0] = ii; P[1][1] = kk; P[1][2] = ii;
                P[2][0] = kk; P[2][1] = ii; P[2][2] = ii;
            } else if (jj == kk) {
                np = 3;
                P[0][0] = ii; P[0][1] = jj; P[0][2] = jj;
                P[1][0] = jj; P[1][1] = ii; P[1][2] = jj;
                P[2][0] = jj; P[2][1] = jj; P[2][2] = ii;
            } else {
                np = 6;
                P[0][0] = ii; P[0][1] = jj; P[0][2] = kk;
                P[1][0] = ii; P[1][1] = kk; P[1][2] = jj;
                P[2][0] = jj; P[2][1] = ii; P[2][2] = kk;
                P[3][0] = jj; P[3][1] = kk; P[3][2] = ii;
                P[4][0] = kk; P[4][1] = ii; P[4][2] = jj;
                P[5][0] = kk; P[5][1] = jj; P[5][2] = ii;
            }
            float s = 0.f;
            if (tid < 23) {
                for (int p = 0; p < np; p++)
                    s += U3_s[((P[p][0] * NI + P[p][1]) * NI + P[p][2]) * 23 + tid];
            } else {
                int a = (tid - 23) / 30, t = (tid - 23) % 30;
                for (int p = 0; p < np; p++)
                    s += U3_v[(((a * NI + P[p][0]) * NI + P[p][1]) * NI + P[p][2]) * 30 + t];
            }
            sym[tid] = s;
        }
        __syncthreads();
        const int c = tid;
        float s = 0.f, v0 = 0.f, v1 = 0.f, v2 = 0.f;
        #pragma unroll
        for (int t = 0; t < 23; t++)
            s = fmaf(sym[t], W3_s[(e * 23 + t) * NC + c], s);
        #pragma unroll
        for (int t = 0; t < 30; t++) {
            float wv = W3_v[(e * 30 + t) * NC + c];
            v0 = fmaf(sym[23 + t], wv, v0);
            v1 = fmaf(sym[53 + t], wv, v1);
            v2 = fmaf(sym[83 + t], wv, v2);
        }
        TA3[(m * NE + e) * NC + c] = make_float2(s, v0);
        TA3[(m * NE + e) * NC + c + PARTN] = make_float2(v1, v2);
    } else if (m < N_TRI + N_PAIR) {
        const int mm = m - N_TRI;
        if (tid < 15) {
            int ii = 0, jj = 0, cnt = 0;
            for (int i = 0; i < NI; i++)
                for (int j = i; j < NI; j++) {
                    if (cnt == mm) { ii = i; jj = j; }
                    cnt++;
                }
            float s;
            if (tid < 3) {
                s = U2_s[(ii * NI + jj) * 3 + tid];
                if (ii != jj) s += U2_s[(jj * NI + ii) * 3 + tid];
            } else {
                int a = (tid - 3) / 4, t = (tid - 3) % 4;
                s = U2_v[((a * NI + ii) * NI + jj) * 4 + t];
                if (ii != jj) s += U2_v[((a * NI + jj) * NI + ii) * 4 + t];
            }
            sym[tid] = s;
        }
        __syncthreads();
        const int c = tid;
        float s = 0.f, v0 = 0.f, v1 = 0.f, v2 = 0.f;
        #pragma unroll
        for (int t = 0; t < 3; t++)
            s = fmaf(sym[t], W2_s[(e * 3 + t) * NC + c], s);
        #pragma unroll
        for (int t = 0; t < 4; t++) {
            float wv = W2_v[(e * 4 + t) * NC + c];
            v0 = fmaf(sym[3 + t],  wv, v0);
            v1 = fmaf(sym[7 + t],  wv, v1);
            v2 = fmaf(sym[11 + t], wv, v2);
        }
        TA2[(mm * NE + e) * NC + c] = make_float2(s, v0);
        TA2[(mm * NE + e) * NC + c + PARTN] = make_float2(v1, v2);
    } else {
        const int i = m - N_TRI - N_PAIR;
        const int c = tid;
        float w1s = W1_s[e * NC + c], w1v = W1_v[e * NC + c];
        TA1[(i * NE + e) * NC + c] = make_float2(U1_s[i] * w1s,
                                                 U1_v[0 * NI + i] * w1v);
        TA1[(i * NE + e) * NC + c + PARTN] = make_float2(U1_v[1 * NI + i] * w1v,
                                                         U1_v[2 * NI + i] * w1v);
    }
}

// ---------------- main ----------------
// grid dim3(512, 2) x 128 threads. wave = 64 c-lanes x 2 waves (b-groups).
// blockIdx.y = channel partition. Each thread: 8 b x 1 c x 2 ch.
__device__ __forceinline__ void step_acc(const v2f (&buf)[NE], float phi,
                                         const float* __restrict__ wn,
                                         v2f& acc)
{
    v2f ts = buf[0] * splat2(wn[0]);
    #pragma unroll
    for (int e = 1; e < NE; e++)
        ts = __builtin_elementwise_fma(buf[e], splat2(wn[e]), ts);
    acc = __builtin_elementwise_fma(splat2(phi), ts, acc);
}

__global__ __launch_bounds__(128) void sc_main(
    const float* __restrict__ x, const float* __restrict__ y,
    const float* __restrict__ ws, float* __restrict__ out)
{
    const int tid = threadIdx.x;
    const int tx  = tid & 63;
    const int tyu = __builtin_amdgcn_readfirstlane(tid >> 6);  // wave-uniform
    const int bx  = blockIdx.x;
    const int part = blockIdx.y;
    const int xcd    = bx & 7;
    const int c_tile = xcd >> 1;               // XCD pair owns one c-slice of T
    const int b_tile = ((bx >> 3) << 1) | (xcd & 1);
    const int c  = (c_tile << 6) + tx;
    const int b0 = (b_tile << 4) + (tyu << 3); // uniform

    // x staging: own-slot -> no barrier; b32 reads, lanes consecutive -> clean.
    __shared__ float xs[2][NI][BT][64];
    #pragma unroll
    for (int n = 0; n < BT; n++) {
        const float* xp = x + ((size_t)(b0 + n) * NC + c) * NI;
        #pragma unroll
        for (int i = 0; i < NI; i++) xs[tyu][i][n][tx] = xp[i];
    }
    const float* xb = &xs[tyu][0][0][tx];   // xb[(i*BT+n)*64]

    // y weights: uniform address -> s_load -> SGPRs
    float w[BT][NE];
    #pragma unroll
    for (int n = 0; n < BT; n++)
        #pragma unroll
        for (int e = 0; e < NE; e++) w[n][e] = y[(b0 + n) * NE + e];

    v2f acc[BT];
    #pragma unroll
    for (int n = 0; n < BT; n++) acc[n] = splat2(0.f);

    const v2f* __restrict__ T3 = (const v2f*)ws + (size_t)part * PARTN;
    const v2f* __restrict__ T2 = T3 + A3N;
    const v2f* __restrict__ T1 = T2 + A2N;

    // ---- triples: 165 rows, unroll-2 with A/B buffers ----
    {
        v2f bufA[NE], bufB[NE];
        #pragma unroll
        for (int e = 0; e < NE; e++) bufA[e] = T3[e * NC + c];  // row 0
        int i = 0, j = 0, k = 0;
        for (int m = 0; m < N_TRI - 1; m += 2) {
            #pragma unroll
            for (int e = 0; e < NE; e++) bufB[e] = T3[((m + 1) * NE + e) * NC + c];
            {   // compute row m with bufA
                float b1 = 0;  (void)b1;
                #pragma unroll
                for (int n = 0; n < BT; n++) {
                    float ph = xb[(i * BT + n) * 64] * xb[(j * BT + n) * 64]
                             * xb[(k * BT + n) * 64];
                    step_acc(bufA, ph, w[n], acc[n]);
                }
            }
            k++; if (k == NI) { j++; if (j == NI) { i++; j = i; } k = j; }
            const int mp = (m + 2 < N_TRI) ? m + 2 : N_TRI - 1;
            #pragma unroll
            for (int e = 0; e < NE; e++) bufA[e] = T3[(mp * NE + e) * NC + c];
            {   // compute row m+1 with bufB
                #pragma unroll
                for (int n = 0; n < BT; n++) {
                    float ph = xb[(i * BT + n) * 64] * xb[(j * BT + n) * 64]
                             * xb[(k * BT + n) * 64];
                    step_acc(bufB, ph, w[n], acc[n]);
                }
            }
            k++; if (k == NI) { j++; if (j == NI) { i++; j = i; } k = j; }
        }
        // tail row 164 (in bufA)
        #pragma unroll
        for (int n = 0; n < BT; n++) {
            float ph = xb[(i * BT + n) * 64] * xb[(j * BT + n) * 64]
                     * xb[(k * BT + n) * 64];
            step_acc(bufA, ph, w[n], acc[n]);
        }
    }

    // ---- pairs: 45 rows, same pattern ----
    {
        v2f bufA[NE], bufB[NE];
        #pragma unroll
        for (int e = 0; e < NE; e++) bufA[e] = T2[e * NC + c];  // row 0
        int i = 0, j = 0;
        for (int m = 0; m < N_PAIR - 1; m += 2) {
            #pragma unroll
            for (int e = 0; e < NE; e++) bufB[e] = T2[((m + 1) * NE + e) * NC + c];
            #pragma unroll
            for (int n = 0; n < BT; n++) {
                float ph = xb[(i * BT + n) * 64] * xb[(j * BT + n) * 64];
                step_acc(bufA, ph, w[n], acc[n]);
            }
            j++; if (j == NI) { i++; j = i; }
            const int mp = (m + 2 < N_PAIR) ? m + 2 : N_PAIR - 1;
            #pragma unroll
            for (int e = 0; e < NE; e++) bufA[e] = T2[(mp * NE + e) * NC + c];
            #pragma unroll
            for (int n = 0; n < BT; n++) {
                float ph = xb[(i * BT + n) * 64] * xb[(j * BT + n) * 64];
                step_acc(bufB, ph, w[n], acc[n]);
            }
            j++; if (j == NI) { i++; j = i; }
        }
        // tail row 44 (in bufA)
        #pragma unroll
        for (int n = 0; n < BT; n++) {
            float ph = xb[(i * BT + n) * 64] * xb[(j * BT + n) * 64];
            step_acc(bufA, ph, w[n], acc[n]);
        }
    }

    // ---- singles: 9 rows ----
    for (int i = 0; i < NI; i++) {
        v2f buf[NE];
        #pragma unroll
        for (int e = 0; e < NE; e++) buf[e] = T1[(i * NE + e) * NC + c];
        #pragma unroll
        for (int n = 0; n < BT; n++)
            step_acc(buf, xb[(i * BT + n) * 64], w[n], acc[n]);
    }

    // out row: [ out_s (256) | out_v (3c+a) ]
    // part 0 holds (s, v0); part 1 holds (v1, v2) -> disjoint stores.
    #pragma unroll
    for (int n = 0; n < BT; n++) {
        float* ob = out + (size_t)(b0 + n) * (4 * NC);
        if (part == 0) {
            ob[c] = acc[n].x;
            ob[NC + 3 * c + 0] = acc[n].y;
        } else {
            ob[NC + 3 * c + 1] = acc[n].x;
            ob[NC + 3 * c + 2] = acc[n].y;
        }
    }
}

extern "C" void kernel_launch(void* const* d_in, const int* in_sizes, int n_in,
                              void* d_out, int out_size, void* d_ws, size_t ws_size,
                              hipStream_t stream) {
    const float* x    = (const float*)d_in[0];
    const float* y    = (const float*)d_in[1];
    const float* U1_s = (const float*)d_in[2];
    const float* U2_s = (const float*)d_in[3];
    const float* U3_s = (const float*)d_in[4];
    const float* U1_v = (const float*)d_in[5];
    const float* U2_v = (const float*)d_in[6];
    const float* U3_v = (const float*)d_in[7];
    const float* W1_s = (const float*)d_in[8];
    const float* W2_s = (const float*)d_in[9];
    const float* W3_s = (const float*)d_in[10];
    const float* W1_v = (const float*)d_in[11];
    const float* W2_v = (const float*)d_in[12];
    const float* W3_v = (const float*)d_in[13];
    float* out = (float*)d_out;
    float* ws  = (float*)d_ws;   // 8.97 MB T tables, rebuilt every call

    sc_prep<<<dim3(N_TRI + N_PAIR + NI, NE), 256, 0, stream>>>(
        U1_s, U2_s, U3_s, U1_v, U2_v, U3_v,
        W1_s, W2_s, W3_s, W1_v, W2_v, W3_v, ws);
    sc_main<<<dim3(512, 2), 128, 0, stream>>>(x, y, ws, out);
}

// Round 6
// 336.531 us; speedup vs baseline: 1.4263x; 1.4263x over previous
//
#include <hip/hip_runtime.h>
#include <hip/hip_bf16.h>

// Symmetric contraction (MACE-style), B=2048, C=256, I=9, E=10. fp32 only
// (fp32 absmax 0.5 vs threshold 7.24; bf16/MFMA numerically dead).
//
// Round-6 = round-4 main loop (validated: float4 T row in regs reused across
// 8 b's, scalar FMAs, m+1 register prefetch) + occupancy fix via m-SPLIT:
//   blockIdx.y=0 -> triple rows [0,110); =1 -> triples [110,165)+pairs+singles
//   (~equal cost). Total T traffic unchanged; waves/SIMD 1 -> 2.
//   Outputs combined via fp32 atomicAdd onto zeroed d_out (commutative ->
//   deterministic; 2 adds/address).
// r5 lesson: do NOT restructure the inner loop (ts-per-n / v2f scalarized ->
// 2x busy cycles). r2 lesson: no waves/EU launch-bounds cap.
// prep: 219 blocks, e-loop inside (sym built once per m, 10x fewer blocks).

#define NB 2048
#define NC 256
#define NI 9
#define NE 10

#define N_TRI 165
#define N_PAIR 45
#define BT 8

// T layout (float4): T3 [165][10][256] | T2 [45][10][256] | T1 [9][10][256]
#define T3N (N_TRI * NE * NC)
#define T2N (N_PAIR * NE * NC)
#define T1N (NI * NE * NC)
// 8.97 MB total in d_ws

// m-split boundary: 110 even rows part0 / 55+45+9=109 part1.
// m=110 decodes to sorted triple (3,3,4)  [i=0:45 rows, i=1:36, i=2:28 -> m109=(3,3,3)]
#define MSPLIT 110

// ---------------- prep: Sym (LDS) x W -> T, e-loop inside ----------------
// grid 219 x 256 threads.
__global__ __launch_bounds__(256) void sc_prep(
    const float* __restrict__ U1_s, const float* __restrict__ U2_s,
    const float* __restrict__ U3_s, const float* __restrict__ U1_v,
    const float* __restrict__ U2_v, const float* __restrict__ U3_v,
    const float* __restrict__ W1_s, const float* __restrict__ W2_s,
    const float* __restrict__ W3_s, const float* __restrict__ W1_v,
    const float* __restrict__ W2_v, const float* __restrict__ W3_v,
    float* __restrict__ ws)
{
    const int m = blockIdx.x;    // 0..218
    const int tid = threadIdx.x; // 0..255
    float4* __restrict__ T3 = (float4*)ws;
    float4* __restrict__ T2 = T3 + T3N;
    float4* __restrict__ T1 = T2 + T2N;

    __shared__ float sym[128];

    if (m < N_TRI) {
        if (tid < 113) {
            int ii = 0, jj = 0, kk = 0, cnt = 0;
            for (int i = 0; i < NI; i++)
                for (int j = i; j < NI; j++)
                    for (int k = j; k < NI; k++) {
                        if (cnt == m) { ii = i; jj = j; kk = k; }
                        cnt++;
                    }
            int P[6][3]; int np;
            if (ii == jj && jj == kk) {
                np = 1;
                P[0][0] = ii; P[0][1] = ii; P[0][2] = ii;
            } else if (ii == jj) {
                np = 3;
                P[0][0] = ii; P[0][1] = ii; P[0][2] = kk;
                P[1][0] = ii; P[1][1] = kk; P[1][2] = ii;
                P[2][0] = kk; P[2][1] = ii; P[2][2] = ii;
            } else if (jj == kk) {
                np = 3;
                P[0][0] = ii; P[0][1] = jj; P[0][2] = jj;
                P[1][0] = jj; P[1][1] = ii; P[1][2] = jj;
                P[2][0] = jj; P[2][1] = jj; P[2][2] = ii;
            } else {
                np = 6;
                P[0][0] = ii; P[0][1] = jj; P[0][2] = kk;
                P[1][0] = ii; P[1][1] = kk; P[1][2] = jj;
                P[2][0] = jj; P[2][1] = ii; P[2][2] = kk;
                P[3][0] = jj; P[3][1] = kk; P[3][2] = ii;
                P[4][0] = kk; P[4][1] = ii; P[4][2] = jj;
                P[5][0] = kk; P[5][1] = jj; P[5][2] = ii;
            }
            float s = 0.f;
            if (tid < 23) {
                for (int p = 0; p < np; p++)
                    s += U3_s[((P[p][0] * NI + P[p][1]) * NI + P[p][2]) * 23 + tid];
            } else {
                int a = (tid - 23) / 30, t = (tid - 23) % 30;
                for (int p = 0; p < np; p++)
                    s += U3_v[(((a * NI + P[p][0]) * NI + P[p][1]) * NI + P[p][2]) * 30 + t];
            }
            sym[tid] = s;
        }
        __syncthreads();
        const int c = tid;
        for (int e = 0; e < NE; e++) {
            float s = 0.f, v0 = 0.f, v1 = 0.f, v2 = 0.f;
            #pragma unroll
            for (int t = 0; t < 23; t++)
                s = fmaf(sym[t], W3_s[(e * 23 + t) * NC + c], s);
            #pragma unroll
            for (int t = 0; t < 30; t++) {
                float wv = W3_v[(e * 30 + t) * NC + c];
                v0 = fmaf(sym[23 + t], wv, v0);
                v1 = fmaf(sym[53 + t], wv, v1);
                v2 = fmaf(sym[83 + t], wv, v2);
            }
            T3[(m * NE + e) * NC + c] = make_float4(s, v0, v1, v2);
        }
    } else if (m < N_TRI + N_PAIR) {
        const int mm = m - N_TRI;
        if (tid < 15) {
            int ii = 0, jj = 0, cnt = 0;
            for (int i = 0; i < NI; i++)
                for (int j = i; j < NI; j++) {
                    if (cnt == mm) { ii = i; jj = j; }
                    cnt++;
                }
            float s;
            if (tid < 3) {
                s = U2_s[(ii * NI + jj) * 3 + tid];
                if (ii != jj) s += U2_s[(jj * NI + ii) * 3 + tid];
            } else {
                int a = (tid - 3) / 4, t = (tid - 3) % 4;
                s = U2_v[((a * NI + ii) * NI + jj) * 4 + t];
                if (ii != jj) s += U2_v[((a * NI + jj) * NI + ii) * 4 + t];
            }
            sym[tid] = s;
        }
        __syncthreads();
        const int c = tid;
        for (int e = 0; e < NE; e++) {
            float s = 0.f, v0 = 0.f, v1 = 0.f, v2 = 0.f;
            #pragma unroll
            for (int t = 0; t < 3; t++)
                s = fmaf(sym[t], W2_s[(e * 3 + t) * NC + c], s);
            #pragma unroll
            for (int t = 0; t < 4; t++) {
                float wv = W2_v[(e * 4 + t) * NC + c];
                v0 = fmaf(sym[3 + t],  wv, v0);
                v1 = fmaf(sym[7 + t],  wv, v1);
                v2 = fmaf(sym[11 + t], wv, v2);
            }
            T2[(mm * NE + e) * NC + c] = make_float4(s, v0, v1, v2);
        }
    } else {
        const int i = m - N_TRI - N_PAIR;
        const int c = tid;
        for (int e = 0; e < NE; e++) {
            float w1s = W1_s[e * NC + c], w1v = W1_v[e * NC + c];
            T1[(i * NE + e) * NC + c] = make_float4(
                U1_s[i] * w1s,
                U1_v[0 * NI + i] * w1v,
                U1_v[1 * NI + i] * w1v,
                U1_v[2 * NI + i] * w1v);
        }
    }
}

// ---------------- main ----------------
// grid dim3(512, 2) x 128 threads; wave = 64 c-lanes, 2 waves (b-groups).
// blockIdx.y = m-partition. Each thread: 8 b x 1 c x 4 ch, atomicAdd out.
__device__ __forceinline__ void tri_advance(int& i, int& j, int& k) {
    k++;
    if (k == NI) { j++; if (j == NI) { i++; j = i; } k = j; }
}

template <int M0, int M1, int I0, int J0, int K0>
__device__ __forceinline__ void do_triples(
    const float4* __restrict__ T3, int c, const float* __restrict__ xb,
    const float (&w)[NE][BT], float (&acc)[BT][4])
{
    float4 bufA[NE], bufB[NE];
    #pragma unroll
    for (int e = 0; e < NE; e++) bufA[e] = T3[(M0 * NE + e) * NC + c];
    int i = I0, j = J0, k = K0;
    for (int m = M0; m + 1 < M1; m += 2) {
        #pragma unroll
        for (int e = 0; e < NE; e++) bufB[e] = T3[((m + 1) * NE + e) * NC + c];
        {
            float phi[BT];
            #pragma unroll
            for (int n = 0; n < BT; n++)
                phi[n] = xb[(i * BT + n) * 64] * xb[(j * BT + n) * 64]
                       * xb[(k * BT + n) * 64];
            #pragma unroll
            for (int e = 0; e < NE; e++) {
                const float4 t = bufA[e];
                #pragma unroll
                for (int n = 0; n < BT; n++) {
                    const float p = w[e][n] * phi[n];
                    acc[n][0] = fmaf(p, t.x, acc[n][0]);
                    acc[n][1] = fmaf(p, t.y, acc[n][1]);
                    acc[n][2] = fmaf(p, t.z, acc[n][2]);
                    acc[n][3] = fmaf(p, t.w, acc[n][3]);
                }
            }
        }
        tri_advance(i, j, k);
        const int mp = (m + 2 < M1) ? m + 2 : M1 - 1;
        #pragma unroll
        for (int e = 0; e < NE; e++) bufA[e] = T3[(mp * NE + e) * NC + c];
        {
            float phi[BT];
            #pragma unroll
            for (int n = 0; n < BT; n++)
                phi[n] = xb[(i * BT + n) * 64] * xb[(j * BT + n) * 64]
                       * xb[(k * BT + n) * 64];
            #pragma unroll
            for (int e = 0; e < NE; e++) {
                const float4 t = bufB[e];
                #pragma unroll
                for (int n = 0; n < BT; n++) {
                    const float p = w[e][n] * phi[n];
                    acc[n][0] = fmaf(p, t.x, acc[n][0]);
                    acc[n][1] = fmaf(p, t.y, acc[n][1]);
                    acc[n][2] = fmaf(p, t.z, acc[n][2]);
                    acc[n][3] = fmaf(p, t.w, acc[n][3]);
                }
            }
        }
        tri_advance(i, j, k);
    }
    if ((M1 - M0) & 1) {   // tail row M1-1 sits in bufA
        float phi[BT];
        #pragma unroll
        for (int n = 0; n < BT; n++)
            phi[n] = xb[(i * BT + n) * 64] * xb[(j * BT + n) * 64]
                   * xb[(k * BT + n) * 64];
        #pragma unroll
        for (int e = 0; e < NE; e++) {
            const float4 t = bufA[e];
            #pragma unroll
            for (int n = 0; n < BT; n++) {
                const float p = w[e][n] * phi[n];
                acc[n][0] = fmaf(p, t.x, acc[n][0]);
                acc[n][1] = fmaf(p, t.y, acc[n][1]);
                acc[n][2] = fmaf(p, t.z, acc[n][2]);
                acc[n][3] = fmaf(p, t.w, acc[n][3]);
            }
        }
    }
}

__global__ __launch_bounds__(128) void sc_main(
    const float* __restrict__ x, const float* __restrict__ y,
    const float* __restrict__ ws, float* __restrict__ out)
{
    const int tid = threadIdx.x;
    const int tx  = tid & 63;
    const int tyu = __builtin_amdgcn_readfirstlane(tid >> 6);  // wave-uniform
    const int bx  = blockIdx.x;
    const int part = blockIdx.y;
    const int xcd    = bx & 7;
    const int c_tile = xcd >> 1;               // XCD pair owns one c-slice of T
    const int b_tile = ((bx >> 3) << 1) | (xcd & 1);
    const int c  = (c_tile << 6) + tx;
    const int b0 = (b_tile << 4) + (tyu << 3); // uniform

    // x staging: own-slot -> no barrier; lanes consecutive -> conflict-free.
    __shared__ float xs[2][NI][BT][64];
    #pragma unroll
    for (int n = 0; n < BT; n++) {
        const float* xp = x + ((size_t)(b0 + n) * NC + c) * NI;
        #pragma unroll
        for (int i = 0; i < NI; i++) xs[tyu][i][n][tx] = xp[i];
    }
    const float* xb = &xs[tyu][0][0][tx];   // xb[(i*BT+n)*64]

    // y weights: uniform address -> s_load
    float w[NE][BT];
    #pragma unroll
    for (int n = 0; n < BT; n++)
        #pragma unroll
        for (int e = 0; e < NE; e++) w[e][n] = y[(b0 + n) * NE + e];

    float acc[BT][4];
    #pragma unroll
    for (int n = 0; n < BT; n++)
        #pragma unroll
        for (int h = 0; h < 4; h++) acc[n][h] = 0.f;

    const float4* __restrict__ T3 = (const float4*)ws;
    const float4* __restrict__ T2 = T3 + T3N;
    const float4* __restrict__ T1 = T2 + T2N;

    if (part == 0) {
        // triples [0, MSPLIT)
        do_triples<0, MSPLIT, 0, 0, 0>(T3, c, xb, w, acc);
    } else {
        // triples [MSPLIT, 165): m=110 -> (3,3,4)
        do_triples<MSPLIT, N_TRI, 3, 3, 4>(T3, c, xb, w, acc);

        // pairs: 45 rows, unroll-2 A/B (odd -> tail), r4 pattern
        {
            float4 bufA[NE], bufB[NE];
            #pragma unroll
            for (int e = 0; e < NE; e++) bufA[e] = T2[e * NC + c];
            int i = 0, j = 0;
            for (int m = 0; m + 1 < N_PAIR; m += 2) {
                #pragma unroll
                for (int e = 0; e < NE; e++) bufB[e] = T2[((m + 1) * NE + e) * NC + c];
                {
                    float phi[BT];
                    #pragma unroll
                    for (int n = 0; n < BT; n++)
                        phi[n] = xb[(i * BT + n) * 64] * xb[(j * BT + n) * 64];
                    #pragma unroll
                    for (int e = 0; e < NE; e++) {
                        const float4 t = bufA[e];
                        #pragma unroll
                        for (int n = 0; n < BT; n++) {
                            const float p = w[e][n] * phi[n];
                            acc[n][0] = fmaf(p, t.x, acc[n][0]);
                            acc[n][1] = fmaf(p, t.y, acc[n][1]);
                            acc[n][2] = fmaf(p, t.z, acc[n][2]);
                            acc[n][3] = fmaf(p, t.w, acc[n][3]);
                        }
                    }
                }
                j++; if (j == NI) { i++; j = i; }
                const int mp = (m + 2 < N_PAIR) ? m + 2 : N_PAIR - 1;
                #pragma unroll
                for (int e = 0; e < NE; e++) bufA[e] = T2[(mp * NE + e) * NC + c];
                {
                    float phi[BT];
                    #pragma unroll
                    for (int n = 0; n < BT; n++)
                        phi[n] = xb[(i * BT + n) * 64] * xb[(j * BT + n) * 64];
                    #pragma unroll
                    for (int e = 0; e < NE; e++) {
                        const float4 t = bufB[e];
                        #pragma unroll
                        for (int n = 0; n < BT; n++) {
                            const float p = w[e][n] * phi[n];
                            acc[n][0] = fmaf(p, t.x, acc[n][0]);
                            acc[n][1] = fmaf(p, t.y, acc[n][1]);
                            acc[n][2] = fmaf(p, t.z, acc[n][2]);
                            acc[n][3] = fmaf(p, t.w, acc[n][3]);
                        }
                    }
                }
                j++; if (j == NI) { i++; j = i; }
            }
            // tail row 44 in bufA
            {
                float phi[BT];
                #pragma unroll
                for (int n = 0; n < BT; n++)
                    phi[n] = xb[(i * BT + n) * 64] * xb[(j * BT + n) * 64];
                #pragma unroll
                for (int e = 0; e < NE; e++) {
                    const float4 t = bufA[e];
                    #pragma unroll
                    for (int n = 0; n < BT; n++) {
                        const float p = w[e][n] * phi[n];
                        acc[n][0] = fmaf(p, t.x, acc[n][0]);
                        acc[n][1] = fmaf(p, t.y, acc[n][1]);
                        acc[n][2] = fmaf(p, t.z, acc[n][2]);
                        acc[n][3] = fmaf(p, t.w, acc[n][3]);
                    }
                }
            }
        }

        // singles: 9 rows
        for (int i = 0; i < NI; i++) {
            float4 tc[NE];
            #pragma unroll
            for (int e = 0; e < NE; e++) tc[e] = T1[(i * NE + e) * NC + c];
            float phi[BT];
            #pragma unroll
            for (int n = 0; n < BT; n++) phi[n] = xb[(i * BT + n) * 64];
            #pragma unroll
            for (int e = 0; e < NE; e++) {
                const float4 t = tc[e];
                #pragma unroll
                for (int n = 0; n < BT; n++) {
                    const float p = w[e][n] * phi[n];
                    acc[n][0] = fmaf(p, t.x, acc[n][0]);
                    acc[n][1] = fmaf(p, t.y, acc[n][1]);
                    acc[n][2] = fmaf(p, t.z, acc[n][2]);
                    acc[n][3] = fmaf(p, t.w, acc[n][3]);
                }
            }
        }
    }

    // combine partitions: atomicAdd onto zeroed out (fp32 add commutative,
    // exactly 2 adds/address -> deterministic).
    #pragma unroll
    for (int n = 0; n < BT; n++) {
        float* ob = out + (size_t)(b0 + n) * (4 * NC);
        atomicAdd(&ob[c],              acc[n][0]);
        atomicAdd(&ob[NC + 3 * c + 0], acc[n][1]);
        atomicAdd(&ob[NC + 3 * c + 1], acc[n][2]);
        atomicAdd(&ob[NC + 3 * c + 2], acc[n][3]);
    }
}

extern "C" void kernel_launch(void* const* d_in, const int* in_sizes, int n_in,
                              void* d_out, int out_size, void* d_ws, size_t ws_size,
                              hipStream_t stream) {
    const float* x    = (const float*)d_in[0];
    const float* y    = (const float*)d_in[1];
    const float* U1_s = (const float*)d_in[2];
    const float* U2_s = (const float*)d_in[3];
    const float* U3_s = (const float*)d_in[4];
    const float* U1_v = (const float*)d_in[5];
    const float* U2_v = (const float*)d_in[6];
    const float* U3_v = (const float*)d_in[7];
    const float* W1_s = (const float*)d_in[8];
    const float* W2_s = (const float*)d_in[9];
    const float* W3_s = (const float*)d_in[10];
    const float* W1_v = (const float*)d_in[11];
    const float* W2_v = (const float*)d_in[12];
    const float* W3_v = (const float*)d_in[13];
    float* out = (float*)d_out;
    float* ws  = (float*)d_ws;   // 8.97 MB T table, rebuilt every call

    hipMemsetAsync(out, 0, (size_t)out_size * sizeof(float), stream);
    sc_prep<<<N_TRI + N_PAIR + NI, 256, 0, stream>>>(
        U1_s, U2_s, U3_s, U1_v, U2_v, U3_v,
        W1_s, W2_s, W3_s, W1_v, W2_v, W3_v, ws);
    sc_main<<<dim3(512, 2), 128, 0, stream>>>(x, y, ws, out);
}

// Round 7
// 328.626 us; speedup vs baseline: 1.4606x; 1.0241x over previous
//
#include <hip/hip_runtime.h>
#include <hip/hip_bf16.h>

// Symmetric contraction (MACE-style), B=2048, C=256, I=9, E=10. fp32 only
// (fp32 absmax 0.5 vs threshold 7.24; bf16/MFMA numerically dead).
//
// Round-7 = round-4 inner loop (validated: float4 T row in regs reused across
// 8 b's, scalar FMAs, m+1 register prefetch) + m-split occupancy fix
// (waves/SIMD 1 -> 2), combined via PARTIAL BUFFER + streaming add:
//   part 0: triples [0,110)            -> partial in ws (plain stores)
//   part 1: triples [110,165)+pairs+1s -> out (plain stores)
//   combine: out += partial (float4 grid-stride, ~25 MB traffic)
// r6 lesson: device-scope atomicAdd combine collapsed VALUBusy (42%) and
// produced ms-scale outlier dispatches -> never combine via global atomics.
// r5 lesson: do not restructure the inner loop. r2: no waves/EU cap.
// ws guard: if ws_size < T + partial, fall back to single-partition path.

#define NB 2048
#define NC 256
#define NI 9
#define NE 10

#define N_TRI 165
#define N_PAIR 45
#define BT 8

// T layout (float4): T3 [165][10][256] | T2 [45][10][256] | T1 [9][10][256]
#define T3N (N_TRI * NE * NC)
#define T2N (N_PAIR * NE * NC)
#define T1N (NI * NE * NC)
#define TBYTES ((size_t)(T3N + T2N + T1N) * 16)   // 8,970,240 B

#define MSPLIT 110   // m=110 decodes to (3,3,4); 110 rows / 109 row-units

// ---------------- prep: Sym (LDS) x W -> T, e-loop inside ----------------
__global__ __launch_bounds__(256) void sc_prep(
    const float* __restrict__ U1_s, const float* __restrict__ U2_s,
    const float* __restrict__ U3_s, const float* __restrict__ U1_v,
    const float* __restrict__ U2_v, const float* __restrict__ U3_v,
    const float* __restrict__ W1_s, const float* __restrict__ W2_s,
    const float* __restrict__ W3_s, const float* __restrict__ W1_v,
    const float* __restrict__ W2_v, const float* __restrict__ W3_v,
    float* __restrict__ ws)
{
    const int m = blockIdx.x;    // 0..218
    const int tid = threadIdx.x; // 0..255
    float4* __restrict__ T3 = (float4*)ws;
    float4* __restrict__ T2 = T3 + T3N;
    float4* __restrict__ T1 = T2 + T2N;

    __shared__ float sym[128];

    if (m < N_TRI) {
        if (tid < 113) {
            int ii = 0, jj = 0, kk = 0, cnt = 0;
            for (int i = 0; i < NI; i++)
                for (int j = i; j < NI; j++)
                    for (int k = j; k < NI; k++) {
                        if (cnt == m) { ii = i; jj = j; kk = k; }
                        cnt++;
                    }
            int P[6][3]; int np;
            if (ii == jj && jj == kk) {
                np = 1;
                P[0][0] = ii; P[0][1] = ii; P[0][2] = ii;
            } else if (ii == jj) {
                np = 3;
                P[0][0] = ii; P[0][1] = ii; P[0][2] = kk;
                P[1][0] = ii; P[1][1] = kk; P[1][2] = ii;
                P[2][0] = kk; P[2][1] = ii; P[2][2] = ii;
            } else if (jj == kk) {
                np = 3;
                P[0][0] = ii; P[0][1] = jj; P[0][2] = jj;
                P[1][0] = jj; P[1][1] = ii; P[1][2] = jj;
                P[2][0] = jj; P[2][1] = jj; P[2][2] = ii;
            } else {
                np = 6;
                P[0][0] = ii; P[0][1] = jj; P[0][2] = kk;
                P[1][0] = ii; P[1][1] = kk; P[1][2] = jj;
                P[2][0] = jj; P[2][1] = ii; P[2][2] = kk;
                P[3][0] = jj; P[3][1] = kk; P[3][2] = ii;
                P[4][0] = kk; P[4][1] = ii; P[4][2] = jj;
                P[5][0] = kk; P[5][1] = jj; P[5][2] = ii;
            }
            float s = 0.f;
            if (tid < 23) {
                for (int p = 0; p < np; p++)
                    s += U3_s[((P[p][0] * NI + P[p][1]) * NI + P[p][2]) * 23 + tid];
            } else {
                int a = (tid - 23) / 30, t = (tid - 23) % 30;
                for (int p = 0; p < np; p++)
                    s += U3_v[(((a * NI + P[p][0]) * NI + P[p][1]) * NI + P[p][2]) * 30 + t];
            }
            sym[tid] = s;
        }
        __syncthreads();
        const int c = tid;
        for (int e = 0; e < NE; e++) {
            float s = 0.f, v0 = 0.f, v1 = 0.f, v2 = 0.f;
            #pragma unroll
            for (int t = 0; t < 23; t++)
                s = fmaf(sym[t], W3_s[(e * 23 + t) * NC + c], s);
            #pragma unroll
            for (int t = 0; t < 30; t++) {
                float wv = W3_v[(e * 30 + t) * NC + c];
                v0 = fmaf(sym[23 + t], wv, v0);
                v1 = fmaf(sym[53 + t], wv, v1);
                v2 = fmaf(sym[83 + t], wv, v2);
            }
            T3[(m * NE + e) * NC + c] = make_float4(s, v0, v1, v2);
        }
    } else if (m < N_TRI + N_PAIR) {
        const int mm = m - N_TRI;
        if (tid < 15) {
            int ii = 0, jj = 0, cnt = 0;
            for (int i = 0; i < NI; i++)
                for (int j = i; j < NI; j++) {
                    if (cnt == mm) { ii = i; jj = j; }
                    cnt++;
                }
            float s;
            if (tid < 3) {
                s = U2_s[(ii * NI + jj) * 3 + tid];
                if (ii != jj) s += U2_s[(jj * NI + ii) * 3 + tid];
            } else {
                int a = (tid - 3) / 4, t = (tid - 3) % 4;
                s = U2_v[((a * NI + ii) * NI + jj) * 4 + t];
                if (ii != jj) s += U2_v[((a * NI + jj) * NI + ii) * 4 + t];
            }
            sym[tid] = s;
        }
        __syncthreads();
        const int c = tid;
        for (int e = 0; e < NE; e++) {
            float s = 0.f, v0 = 0.f, v1 = 0.f, v2 = 0.f;
            #pragma unroll
            for (int t = 0; t < 3; t++)
                s = fmaf(sym[t], W2_s[(e * 3 + t) * NC + c], s);
            #pragma unroll
            for (int t = 0; t < 4; t++) {
                float wv = W2_v[(e * 4 + t) * NC + c];
                v0 = fmaf(sym[3 + t],  wv, v0);
                v1 = fmaf(sym[7 + t],  wv, v1);
                v2 = fmaf(sym[11 + t], wv, v2);
            }
            T2[(mm * NE + e) * NC + c] = make_float4(s, v0, v1, v2);
        }
    } else {
        const int i = m - N_TRI - N_PAIR;
        const int c = tid;
        for (int e = 0; e < NE; e++) {
            float w1s = W1_s[e * NC + c], w1v = W1_v[e * NC + c];
            T1[(i * NE + e) * NC + c] = make_float4(
                U1_s[i] * w1s,
                U1_v[0 * NI + i] * w1v,
                U1_v[1 * NI + i] * w1v,
                U1_v[2 * NI + i] * w1v);
        }
    }
}

// ---------------- main ----------------
__device__ __forceinline__ void tri_advance(int& i, int& j, int& k) {
    k++;
    if (k == NI) { j++; if (j == NI) { i++; j = i; } k = j; }
}

#define ROW_FMA(BUF)                                              \
    {                                                             \
        _Pragma("unroll")                                         \
        for (int e = 0; e < NE; e++) {                            \
            const float4 t = BUF[e];                              \
            _Pragma("unroll")                                     \
            for (int n = 0; n < BT; n++) {                        \
                const float p = w[e][n] * phi[n];                 \
                acc[n][0] = fmaf(p, t.x, acc[n][0]);              \
                acc[n][1] = fmaf(p, t.y, acc[n][1]);              \
                acc[n][2] = fmaf(p, t.z, acc[n][2]);              \
                acc[n][3] = fmaf(p, t.w, acc[n][3]);              \
            }                                                     \
        }                                                         \
    }

template <int M0, int M1, int I0, int J0, int K0>
__device__ __forceinline__ void do_triples(
    const float4* __restrict__ T3, int c, const float* __restrict__ xb,
    const float (&w)[NE][BT], float (&acc)[BT][4])
{
    float4 bufA[NE], bufB[NE];
    #pragma unroll
    for (int e = 0; e < NE; e++) bufA[e] = T3[(M0 * NE + e) * NC + c];
    int i = I0, j = J0, k = K0;
    for (int m = M0; m + 1 < M1; m += 2) {
        #pragma unroll
        for (int e = 0; e < NE; e++) bufB[e] = T3[((m + 1) * NE + e) * NC + c];
        {
            float phi[BT];
            #pragma unroll
            for (int n = 0; n < BT; n++)
                phi[n] = xb[(i * BT + n) * 64] * xb[(j * BT + n) * 64]
                       * xb[(k * BT + n) * 64];
            ROW_FMA(bufA)
        }
        tri_advance(i, j, k);
        const int mp = (m + 2 < M1) ? m + 2 : M1 - 1;
        #pragma unroll
        for (int e = 0; e < NE; e++) bufA[e] = T3[(mp * NE + e) * NC + c];
        {
            float phi[BT];
            #pragma unroll
            for (int n = 0; n < BT; n++)
                phi[n] = xb[(i * BT + n) * 64] * xb[(j * BT + n) * 64]
                       * xb[(k * BT + n) * 64];
            ROW_FMA(bufB)
        }
        tri_advance(i, j, k);
    }
    if ((M1 - M0) & 1) {
        float phi[BT];
        #pragma unroll
        for (int n = 0; n < BT; n++)
            phi[n] = xb[(i * BT + n) * 64] * xb[(j * BT + n) * 64]
                   * xb[(k * BT + n) * 64];
        ROW_FMA(bufA)
    }
}

// grid (512, P) x 128. wave = 64 c-lanes, 2 waves (b-groups) per block.
// full=1 (P=1): every block does all rows, writes out.
// full=0 (P=2): part0 -> triples[0,110) -> pout; part1 -> rest -> out.
__global__ __launch_bounds__(128) void sc_main(
    const float* __restrict__ x, const float* __restrict__ y,
    const float* __restrict__ ws, float* __restrict__ out,
    float* __restrict__ pout, int full)
{
    const int tid = threadIdx.x;
    const int tx  = tid & 63;
    const int tyu = __builtin_amdgcn_readfirstlane(tid >> 6);
    const int bx  = blockIdx.x;
    const int part = blockIdx.y;
    const int xcd    = bx & 7;
    const int c_tile = xcd >> 1;               // XCD pair owns one c-slice of T
    const int b_tile = ((bx >> 3) << 1) | (xcd & 1);
    const int c  = (c_tile << 6) + tx;
    const int b0 = (b_tile << 4) + (tyu << 3); // uniform

    __shared__ float xs[2][NI][BT][64];
    #pragma unroll
    for (int n = 0; n < BT; n++) {
        const float* xp = x + ((size_t)(b0 + n) * NC + c) * NI;
        #pragma unroll
        for (int i = 0; i < NI; i++) xs[tyu][i][n][tx] = xp[i];
    }
    const float* xb = &xs[tyu][0][0][tx];

    float w[NE][BT];
    #pragma unroll
    for (int n = 0; n < BT; n++)
        #pragma unroll
        for (int e = 0; e < NE; e++) w[e][n] = y[(b0 + n) * NE + e];

    float acc[BT][4];
    #pragma unroll
    for (int n = 0; n < BT; n++)
        #pragma unroll
        for (int h = 0; h < 4; h++) acc[n][h] = 0.f;

    const float4* __restrict__ T3 = (const float4*)ws;
    const float4* __restrict__ T2 = T3 + T3N;
    const float4* __restrict__ T1 = T2 + T2N;

    const bool doA = full || part == 0;   // triples [0, MSPLIT)
    const bool doB = full || part == 1;   // triples [MSPLIT,165) + pairs + 1s

    if (doA)
        do_triples<0, MSPLIT, 0, 0, 0>(T3, c, xb, w, acc);

    if (doB) {
        do_triples<MSPLIT, N_TRI, 3, 3, 4>(T3, c, xb, w, acc);

        // pairs: 45 rows, unroll-2 A/B
        {
            float4 bufA[NE], bufB[NE];
            #pragma unroll
            for (int e = 0; e < NE; e++) bufA[e] = T2[e * NC + c];
            int i = 0, j = 0;
            for (int m = 0; m + 1 < N_PAIR; m += 2) {
                #pragma unroll
                for (int e = 0; e < NE; e++) bufB[e] = T2[((m + 1) * NE + e) * NC + c];
                {
                    float phi[BT];
                    #pragma unroll
                    for (int n = 0; n < BT; n++)
                        phi[n] = xb[(i * BT + n) * 64] * xb[(j * BT + n) * 64];
                    ROW_FMA(bufA)
                }
                j++; if (j == NI) { i++; j = i; }
                const int mp = (m + 2 < N_PAIR) ? m + 2 : N_PAIR - 1;
                #pragma unroll
                for (int e = 0; e < NE; e++) bufA[e] = T2[(mp * NE + e) * NC + c];
                {
                    float phi[BT];
                    #pragma unroll
                    for (int n = 0; n < BT; n++)
                        phi[n] = xb[(i * BT + n) * 64] * xb[(j * BT + n) * 64];
                    ROW_FMA(bufB)
                }
                j++; if (j == NI) { i++; j = i; }
            }
            {   // tail row 44 in bufA
                float phi[BT];
                #pragma unroll
                for (int n = 0; n < BT; n++)
                    phi[n] = xb[(i * BT + n) * 64] * xb[(j * BT + n) * 64];
                ROW_FMA(bufA)
            }
        }

        // singles
        for (int i = 0; i < NI; i++) {
            float4 tc[NE];
            #pragma unroll
            for (int e = 0; e < NE; e++) tc[e] = T1[(i * NE + e) * NC + c];
            float phi[BT];
            #pragma unroll
            for (int n = 0; n < BT; n++) phi[n] = xb[(i * BT + n) * 64];
            ROW_FMA(tc)
        }
    }

    float* __restrict__ dst = (!full && part == 0) ? pout : out;
    #pragma unroll
    for (int n = 0; n < BT; n++) {
        float* ob = dst + (size_t)(b0 + n) * (4 * NC);
        ob[c] = acc[n][0];
        ob[NC + 3 * c + 0] = acc[n][1];
        ob[NC + 3 * c + 1] = acc[n][2];
        ob[NC + 3 * c + 2] = acc[n][3];
    }
}

// out += partial (float4 grid-stride)
__global__ __launch_bounds__(256) void sc_combine(
    float4* __restrict__ out, const float4* __restrict__ p, int n4)
{
    int i = blockIdx.x * 256 + threadIdx.x;
    if (i < n4) {
        float4 a = out[i], b = p[i];
        out[i] = make_float4(a.x + b.x, a.y + b.y, a.z + b.z, a.w + b.w);
    }
}

extern "C" void kernel_launch(void* const* d_in, const int* in_sizes, int n_in,
                              void* d_out, int out_size, void* d_ws, size_t ws_size,
                              hipStream_t stream) {
    const float* x    = (const float*)d_in[0];
    const float* y    = (const float*)d_in[1];
    const float* U1_s = (const float*)d_in[2];
    const float* U2_s = (const float*)d_in[3];
    const float* U3_s = (const float*)d_in[4];
    const float* U1_v = (const float*)d_in[5];
    const float* U2_v = (const float*)d_in[6];
    const float* U3_v = (const float*)d_in[7];
    const float* W1_s = (const float*)d_in[8];
    const float* W2_s = (const float*)d_in[9];
    const float* W3_s = (const float*)d_in[10];
    const float* W1_v = (const float*)d_in[11];
    const float* W2_v = (const float*)d_in[12];
    const float* W3_v = (const float*)d_in[13];
    float* out = (float*)d_out;
    float* ws  = (float*)d_ws;

    const size_t out_bytes = (size_t)out_size * sizeof(float);
    const bool split = ws_size >= TBYTES + out_bytes;   // constant across calls
    float* pout = (float*)((char*)d_ws + TBYTES);

    sc_prep<<<N_TRI + N_PAIR + NI, 256, 0, stream>>>(
        U1_s, U2_s, U3_s, U1_v, U2_v, U3_v,
        W1_s, W2_s, W3_s, W1_v, W2_v, W3_v, ws);

    if (split) {
        sc_main<<<dim3(512, 2), 128, 0, stream>>>(x, y, ws, out, pout, 0);
        const int n4 = out_size / 4;
        sc_combine<<<(n4 + 255) / 256, 256, 0, stream>>>(
            (float4*)out, (const float4*)pout, n4);
    } else {
        sc_main<<<dim3(512, 1), 128, 0, stream>>>(x, y, ws, out, out, 1);
    }
}